// Round 1
// baseline (1089.793 us; speedup 1.0000x reference)
//
#include <hip/hip_runtime.h>

// PainHead: seg-masked conv(600->2048,K9) -> ReLU -> BN -> seg-masked conv(2048->2048,K9)
//           -> ReLU -> BN -> linear(2048->2) -> softmax.
// Runtime dtype detection (flags in ws): floats f32-vs-bf16, seg int64-vs-int32.
// GEMM core: mfma_f32_32x32x16_bf16. Block tile 256x128, 4 waves (2x2) of 128x64 wave
// tiles, grid 512 = 2 blocks/CU. BK=64 (8 channel-groups staged): 289 barriers instead
// of 577 — longer MFMA runs per iter to keep the matrix pipe fed with 2 waves/SIMD.
// A halo: r3/r5-proven FLAT staging (stride 264, strided t-loop, dest = uniform+lane*16).
// B double-buffered, 1 barrier/k-iter. Compute split in two s2-halves to cap VGPRs.
// R6: XCD-aware block swizzle (bijective, 512%8==0), column-chunked so each XCD's 64
// blocks cover 2 output-column panels x all 32 row-blocks -> B panel re-reads hit the
// XCD-private L2 instead of LLC.

typedef unsigned int   u32;
typedef unsigned short u16;
typedef __bf16 bf16x8 __attribute__((ext_vector_type(8)));
typedef float  f32x16 __attribute__((ext_vector_type(16)));

#define NROW 8192
#define DH   2048

__device__ __forceinline__ float b2f(u16 u) {
  union { u32 i; float f; } x; x.i = ((u32)u) << 16; return x.f;
}
__device__ __forceinline__ u16 f2b(float f) {
  union { float f; u32 i; } x; x.f = f;
  u32 r = x.i + 0x7fffu + ((x.i >> 16) & 1u);   // RTNE
  return (u16)(r >> 16);
}
__device__ __forceinline__ void gl_lds16(const void* g, void* l) {
  __builtin_amdgcn_global_load_lds(
      (const __attribute__((address_space(1))) u32*)g,
      (__attribute__((address_space(3))) u32*)l, 16, 0, 0);
}

// ---------------- dtype detection ----------------
__global__ void detect(const void* __restrict__ latent, const void* __restrict__ seg,
                       u32* __restrict__ flags) {
  __shared__ int sane_cnt;
  __shared__ int seg_nz;
  if (threadIdx.x == 0) { sane_cnt = 0; seg_nz = 0; }
  __syncthreads();
  const u16* lu = (const u16*)latent;
  int local = 0;
  for (int i = threadIdx.x; i < 512; i += 256) {
    u16 u = lu[2 * i];
    int e = (u >> 7) & 0xFF;
    if (u == 0 || (e >= 90 && e <= 145)) local++;
  }
  atomicAdd(&sane_cnt, local);
  const int* s32 = (const int*)seg;
  int nz = 0;
  for (int i = threadIdx.x; i < 1000; i += 256)
    nz |= s32[6001 + 2 * i];
  atomicOr(&seg_nz, nz);
  __syncthreads();
  if (threadIdx.x == 0) {
    flags[0] = (sane_cnt >= 450) ? 1u : 0u;   // bf16?
    flags[1] = (seg_nz == 0) ? 1u : 0u;       // int64?
  }
}

// ---------------- preprocessing ----------------
__global__ void prep_masks(const void* __restrict__ seg, const u32* __restrict__ flags,
                           u32* __restrict__ masks) {
  int n = blockIdx.x * 256 + threadIdx.x;
  u32 b = 0;
  if (flags[1]) {
    const long long* s = (const long long*)seg;
    long long sn = s[n];
    #pragma unroll
    for (int k = 0; k < 9; ++k) {
      int m = n + k - 4;
      if (m >= 0 && m < NROW && s[m] == sn) b |= (1u << k);
    }
  } else {
    const int* s = (const int*)seg;
    int sn = s[n];
    #pragma unroll
    for (int k = 0; k < 9; ++k) {
      int m = n + k - 4;
      if (m >= 0 && m < NROW && s[m] == sn) b |= (1u << k);
    }
  }
  masks[n] = b;
}

__global__ void prep_x1t(const void* __restrict__ latent, const u32* __restrict__ flags,
                         u16* __restrict__ X1t) {
  int tid = blockIdx.x * 256 + threadIdx.x;     // 80*8192 threads
  int n = tid & (NROW - 1), g = tid >> 13;
  union { u16 o[8]; uint4 v; } u;
  u.v = make_uint4(0, 0, 0, 0);
  if (g < 75) {
    if (flags[0]) {
      u.v = *(const uint4*)((const u16*)latent + (size_t)n * 600 + g * 8);
    } else {
      const float* lf = (const float*)latent + (size_t)n * 600 + g * 8;
      float4 a = *(const float4*)lf;
      float4 b = *(const float4*)(lf + 4);
      u.o[0] = f2b(a.x); u.o[1] = f2b(a.y); u.o[2] = f2b(a.z); u.o[3] = f2b(a.w);
      u.o[4] = f2b(b.x); u.o[5] = f2b(b.y); u.o[6] = f2b(b.z); u.o[7] = f2b(b.w);
    }
  }
  *(uint4*)(X1t + ((size_t)g * NROW + n) * 8) = u.v;
}

// Wt[k][g][d][j] = w[d][8g+j][k] via LDS transpose; coalesced read & write.
// Tile stride 290 u16 (word-stride 145, odd) -> conflict-free transpose reads.
template<int CIN, int G>
__global__ void prep_wt(const void* __restrict__ w, const u32* __restrict__ flags,
                        u16* __restrict__ Wt) {
  __shared__ u16 tile[64 * 290];                 // [dr][m], m = (c-c0)*9+k
  int d0 = blockIdx.x * 64, c0 = blockIdx.y * 32;
  u32 isbf = flags[0];
  int mlim = (CIN - c0) * 9;
  #pragma unroll 1
  for (int it = 0; it < 72; ++it) {
    int e = it * 256 + threadIdx.x;
    int dr = e / 288, m = e - dr * 288;
    u16 val = 0;
    if (m < mlim) {
      size_t si = (size_t)(d0 + dr) * CIN * 9 + (size_t)c0 * 9 + m;
      val = isbf ? ((const u16*)w)[si] : f2b(((const float*)w)[si]);
    }
    tile[dr * 290 + m] = val;
  }
  __syncthreads();
  int g = threadIdx.x >> 6, dd = threadIdx.x & 63;
  #pragma unroll 1
  for (int k = 0; k < 9; ++k) {
    union { u16 o[8]; uint4 v; } u;
    #pragma unroll
    for (int j = 0; j < 8; ++j) u.o[j] = tile[dd * 290 + (g * 8 + j) * 9 + k];
    *(uint4*)(Wt + (((size_t)k * G + (c0 >> 3) + g) * DH + d0 + dd) * 8) = u.v;
  }
}

__device__ __forceinline__ float ldf(const void* p, int i, u32 isbf) {
  return isbf ? b2f(((const u16*)p)[i]) : ((const float*)p)[i];
}

__global__ void prep_bn(const void* __restrict__ b, const void* __restrict__ g,
                        const void* __restrict__ be, const void* __restrict__ m,
                        const void* __restrict__ v, const u32* __restrict__ flags,
                        float* __restrict__ bias_f, float* __restrict__ scale_f,
                        float* __restrict__ shift_f) {
  int i = blockIdx.x * 256 + threadIdx.x;
  u32 isbf = flags[0];
  float sc = ldf(g, i, isbf) * rsqrtf(ldf(v, i, isbf) + 1e-5f);
  bias_f[i]  = ldf(b, i, isbf);
  scale_f[i] = sc;
  shift_f[i] = ldf(be, i, isbf) - ldf(m, i, isbf) * sc;
}

// ---------------- main seg-conv GEMM ----------------
// Xt: [GTOT][NROW][8] bf16, Wt: [9][GTOT][DH][8] bf16.
// Grid: (DH/128, NROW/256), 256 threads = 2x2 waves of 128(row)x64(col) tiles.
// KB = GTOT/8 channel-super-blocks of 64 channels (8 groups).
// OM=0: grouped out [DH/8][NROW][8]; OM=1: row-major [NROW][DH].
template<int GTOT, int KB, int OM>
__launch_bounds__(256, 2)
__global__ void conv_gemm(const u16* __restrict__ Xt, const u16* __restrict__ Wt,
                          const u32* __restrict__ masks,
                          const float* __restrict__ bias_f,
                          const float* __restrict__ scale_f,
                          const float* __restrict__ shift_f,
                          u16* __restrict__ out) {
  __shared__ uint4 A_lds[8 * 264];       // [g][haloRow] flat, stride 264 (proven idiom)
  __shared__ uint4 B_lds[2][8 * 128];    // dbuf [g][col]

  const int tid  = threadIdx.x;
  // XCD-aware swizzle: HW dispatch id round-robins XCDs (xcd = flat % 8).
  // Remap so XCD k owns a contiguous column-major chunk of the logical grid:
  // 64 blocks = 2 full output-column panels x 32 row-blocks -> B hits per-XCD L2.
  // Bijective since nwg = 512 is a multiple of 8. Grid is fixed (16, 32).
  const int flat = (int)(blockIdx.y * gridDim.x + blockIdx.x);
  const int swz  = (flat & 7) * 64 + (flat >> 3);
  const int col0 = (swz >> 5) * 128;     // swz / 32 -> column panel
  const int row0 = (swz & 31) * 256;     // swz % 32 -> row block
  const int lane = tid & 63;
  const int wid  = tid >> 6;
  const int wr = wid >> 1, wc = wid & 1;       // 2x2 waves: 128 rows x 64 cols each
  const int l31 = lane & 31, g2 = lane >> 5;

  f32x16 acc[4][2] = {};

  u32 mb[4];
  #pragma unroll
  for (int i = 0; i < 4; ++i)
    mb[i] = masks[row0 + wr * 128 + i * 32 + l31];

  const int tot = KB * 9;

  #pragma unroll 1
  for (int cb = 0; cb < KB; ++cb) {
    // stage A halo: 8 groups x 264 rows (flat strided loop, proven idiom)
    for (int t = tid; t < 8 * 264; t += 256) {
      int g = t / 264;
      int h = t - g * 264;
      int xr = row0 - 4 + h;
      xr = xr < 0 ? 0 : (xr > NROW - 1 ? NROW - 1 : xr);
      gl_lds16(Xt + (((size_t)(cb * 8 + g)) * NROW + xr) * 8, &A_lds[t]);
    }
    if (cb == 0) {
      // stage B for (cb=0,k=0) into buf 0: 8 groups x 128 cols
      #pragma unroll
      for (int it2 = 0; it2 < 4; ++it2) {
        int t2 = it2 * 256 + tid;
        gl_lds16(Wt + (((size_t)(t2 >> 7)) * DH + col0 + (t2 & 127)) * 8, &B_lds[0][t2]);
      }
    }
    __syncthreads();

    #pragma unroll 1
    for (int k = 0; k < 9; ++k) {
      const int it = cb * 9 + k;
      // prefetch B for next iteration into the other buffer
      if (it + 1 < tot) {
        int k2 = k + 1, cb2 = cb;
        if (k2 == 9) { k2 = 0; cb2 = cb + 1; }
        const u16* src = Wt + (((size_t)k2 * GTOT + cb2 * 8) * DH + col0) * 8;
        uint4* dst = B_lds[(it + 1) & 1];
        #pragma unroll
        for (int it2 = 0; it2 < 4; ++it2) {
          int t2 = it2 * 256 + tid;
          gl_lds16(src + ((size_t)(t2 >> 7) * DH + (t2 & 127)) * 8, &dst[t2]);
        }
      }

      const uint4* bb = B_lds[it & 1];
      // two halves (s2) to cap live registers at ~r5 level
      #pragma unroll 1
      for (int s2 = 0; s2 < 2; ++s2) {
        bf16x8 af[4][2];
        #pragma unroll
        for (int i = 0; i < 4; ++i) {
          int h = wr * 128 + i * 32 + l31 + k;
          bool on = (mb[i] >> k) & 1u;
          #pragma unroll
          for (int s = 0; s < 2; ++s) {
            uint4 a4 = A_lds[(s2 * 4 + 2 * s + g2) * 264 + h];
            if (!on) a4 = make_uint4(0, 0, 0, 0);
            af[i][s] = __builtin_bit_cast(bf16x8, a4);
          }
        }
        bf16x8 bfr[2][2];
        #pragma unroll
        for (int j = 0; j < 2; ++j)
          #pragma unroll
          for (int s = 0; s < 2; ++s)
            bfr[j][s] = __builtin_bit_cast(bf16x8,
                bb[(s2 * 4 + 2 * s + g2) * 128 + wc * 64 + j * 32 + l31]);

        #pragma unroll
        for (int i = 0; i < 4; ++i)
          #pragma unroll
          for (int j = 0; j < 2; ++j)
            #pragma unroll
            for (int s = 0; s < 2; ++s)
              acc[i][j] = __builtin_amdgcn_mfma_f32_32x32x16_bf16(
                  af[i][s], bfr[j][s], acc[i][j], 0, 0, 0);
      }

      __syncthreads();
    }
  }

  // epilogue: bias -> ReLU -> BN -> bf16 store
  float bc[2], sc[2], sh[2];
  int colv[2];
  #pragma unroll
  for (int j = 0; j < 2; ++j) {
    colv[j] = col0 + wc * 64 + j * 32 + l31;
    bc[j] = bias_f[colv[j]]; sc[j] = scale_f[colv[j]]; sh[j] = shift_f[colv[j]];
  }
  #pragma unroll
  for (int i = 0; i < 4; ++i) {
    #pragma unroll
    for (int j = 0; j < 2; ++j) {
      int col = colv[j];
      #pragma unroll
      for (int r = 0; r < 16; ++r) {
        int row = i * 32 + (r & 3) + 8 * (r >> 2) + 4 * g2;  // 32x32 C layout
        int n = row0 + wr * 128 + row;
        float v = acc[i][j][r] + bc[j];
        v = fmaxf(v, 0.f) * sc[j] + sh[j];
        u16 o = f2b(v);
        if (OM == 0) out[(((size_t)(col >> 3)) * NROW + n) * 8 + (col & 7)] = o;
        else         out[(size_t)n * DH + col] = o;
      }
    }
  }
}

// ---------------- final linear + softmax ----------------
__global__ void final_head(const u16* __restrict__ h2, const void* __restrict__ wlin,
                           const void* __restrict__ blin, const u32* __restrict__ flags,
                           void* __restrict__ out) {
  int row  = blockIdx.x * 4 + (threadIdx.x >> 6);
  int lane = threadIdx.x & 63;
  u32 isbf = flags[0];
  const u16* hr = h2 + (size_t)row * DH;
  float s0 = 0.f, s1 = 0.f;
  #pragma unroll
  for (int it = 0; it < 4; ++it) {
    int c = it * 512 + lane * 8;
    uint4 hv = *(const uint4*)(hr + c);
    const u16* hp = (const u16*)&hv;
    float w0v[8], w1v[8];
    if (isbf) {
      uint4 w0 = *(const uint4*)((const u16*)wlin + c);
      uint4 w1 = *(const uint4*)((const u16*)wlin + DH + c);
      const u16* p0 = (const u16*)&w0;
      const u16* p1 = (const u16*)&w1;
      #pragma unroll
      for (int j = 0; j < 8; ++j) { w0v[j] = b2f(p0[j]); w1v[j] = b2f(p1[j]); }
    } else {
      const float* f0 = (const float*)wlin + c;
      const float* f1 = (const float*)wlin + DH + c;
      float4 a0 = *(const float4*)f0, b0 = *(const float4*)(f0 + 4);
      float4 a1 = *(const float4*)f1, b1 = *(const float4*)(f1 + 4);
      w0v[0]=a0.x; w0v[1]=a0.y; w0v[2]=a0.z; w0v[3]=a0.w;
      w0v[4]=b0.x; w0v[5]=b0.y; w0v[6]=b0.z; w0v[7]=b0.w;
      w1v[0]=a1.x; w1v[1]=a1.y; w1v[2]=a1.z; w1v[3]=a1.w;
      w1v[4]=b1.x; w1v[5]=b1.y; w1v[6]=b1.z; w1v[7]=b1.w;
    }
    #pragma unroll
    for (int j = 0; j < 8; ++j) {
      float hf = b2f(hp[j]);
      s0 += hf * w0v[j];
      s1 += hf * w1v[j];
    }
  }
  #pragma unroll
  for (int off = 32; off >= 1; off >>= 1) {
    s0 += __shfl_down(s0, off);
    s1 += __shfl_down(s1, off);
  }
  if (lane == 0) {
    float o0 = s0 + ldf(blin, 0, isbf);
    float o1 = s1 + ldf(blin, 1, isbf);
    float mx = fmaxf(o0, o1);
    float e0 = expf(o0 - mx), e1 = expf(o1 - mx);
    float inv = 1.f / (e0 + e1);
    if (isbf) {
      u16* ob = (u16*)out;
      ob[(size_t)row * 2]              = f2b(o0);
      ob[(size_t)row * 2 + 1]          = f2b(o1);
      ob[16384 + (size_t)row * 2]      = f2b(e0 * inv);
      ob[16384 + (size_t)row * 2 + 1]  = f2b(e1 * inv);
    } else {
      float* of = (float*)out;
      of[(size_t)row * 2]              = o0;
      of[(size_t)row * 2 + 1]          = o1;
      of[16384 + (size_t)row * 2]      = e0 * inv;
      of[16384 + (size_t)row * 2 + 1]  = e1 * inv;
    }
  }
}

// ---------------- launch ----------------
extern "C" void kernel_launch(void* const* d_in, const int* in_sizes, int n_in,
                              void* d_out, int out_size, void* d_ws, size_t ws_size,
                              hipStream_t stream) {
  const void* latent = d_in[0];
  const void* seg    = d_in[1];
  const void* w1  = d_in[2];
  const void* b1  = d_in[3];
  const void* g1  = d_in[4];
  const void* be1 = d_in[5];
  const void* m1  = d_in[6];
  const void* v1  = d_in[7];
  const void* w2  = d_in[8];
  const void* b2  = d_in[9];
  const void* g2  = d_in[10];
  const void* be2 = d_in[11];
  const void* m2  = d_in[12];
  const void* v2  = d_in[13];
  const void* wlin = d_in[14];
  const void* blin = d_in[15];

  char* ws = (char*)d_ws;
  u32*   flags = (u32*)ws;                                   //        256
  u32*   masks = (u32*)(ws + 256);                           //      32768
  float* bn1   = (float*)(ws + 33024);                       //      24576
  float* bn2   = (float*)(ws + 57600);                       //      24576
  u16*   X1t   = (u16*)(ws + 82176);                         //   10485760  [80][8192][8]
  u16*   Wt1   = X1t + (size_t)80 * NROW * 8;                //   23592960  [9][80][2048][8]
  u16*   h1t   = Wt1 + (size_t)9 * 80 * DH * 8;              //   33554432  [256][8192][8]
  u16*   Wt2   = h1t + (size_t)256 * NROW * 8;               //   75497472  [9][256][2048][8]
  u16*   h2    = X1t;                                        // reuse dead X1t/Wt1 region

  detect<<<1, 256, 0, stream>>>(latent, seg, flags);
  prep_masks<<<NROW / 256, 256, 0, stream>>>(seg, flags, masks);
  prep_bn<<<DH / 256, 256, 0, stream>>>(b1, g1, be1, m1, v1, flags, bn1, bn1 + 2048, bn1 + 4096);
  prep_bn<<<DH / 256, 256, 0, stream>>>(b2, g2, be2, m2, v2, flags, bn2, bn2 + 2048, bn2 + 4096);
  prep_x1t<<<(80 * NROW) / 256, 256, 0, stream>>>(latent, flags, X1t);
  prep_wt<600, 80><<<dim3(DH / 64, 20), 256, 0, stream>>>(w1, flags, Wt1);
  prep_wt<2048, 256><<<dim3(DH / 64, 64), 256, 0, stream>>>(w2, flags, Wt2);

  dim3 grid(DH / 128, NROW / 256);
  conv_gemm<80, 10, 0><<<grid, 256, 0, stream>>>(X1t, Wt1, masks,
      bn1, bn1 + 2048, bn1 + 4096, h1t);
  conv_gemm<256, 32, 1><<<grid, 256, 0, stream>>>(h1t, Wt2, masks,
      bn2, bn2 + 2048, bn2 + 4096, h2);

  final_head<<<NROW / 4, 256, 0, stream>>>(h2, wlin, blin, flags, d_out);
}

// Round 2
// 1077.916 us; speedup vs baseline: 1.0110x; 1.0110x over previous
//
#include <hip/hip_runtime.h>

// PainHead: seg-masked conv(600->2048,K9) -> ReLU -> BN -> seg-masked conv(2048->2048,K9)
//           -> ReLU -> BN -> linear(2048->2) -> softmax.
// Runtime dtype detection (flags in ws): floats f32-vs-bf16, seg int64-vs-int32.
// GEMM core: mfma_f32_32x32x16_bf16. Block tile 256x128, 4 waves (2x2) of 128x64 wave
// tiles, grid 512 = 2 blocks/CU. BK=64 (8 channel-groups staged).
// A halo: r3/r5-proven FLAT staging (stride 264, strided t-loop, dest = uniform+lane*16).
// B double-buffered, 1 barrier/k-iter.
// R6: XCD-aware column-chunked block swizzle (bijective, 512%8==0).
// R7: software-pipelined slab schedule inside each k-iter — 4 slabs (one 16-chan
//     MFMA K-step each); issue slab t+1's 6 ds_read_b128 before slab t's 8 MFMAs so
//     LDS latency + mask VALU hide under the matrix pipe (rocprof r1: MFMA 2066 +
//     LDS 1536 + VALU 1350 clk/iter were SERIAL = 4733 measured). Per-thread LDS
//     base pointers -> all reads are ds_read_b128 with immediate offsets (cuts VALU).
//     Wave-uniform clean-chunk test skips boundary cndmask for ~70% of chunks.
//     s_setprio(1) around each MFMA cluster (T5; slab split gives it role diversity).

typedef unsigned int   u32;
typedef unsigned short u16;
typedef __bf16 bf16x8 __attribute__((ext_vector_type(8)));
typedef float  f32x16 __attribute__((ext_vector_type(16)));

#define NROW 8192
#define DH   2048

__device__ __forceinline__ float b2f(u16 u) {
  union { u32 i; float f; } x; x.i = ((u32)u) << 16; return x.f;
}
__device__ __forceinline__ u16 f2b(float f) {
  union { float f; u32 i; } x; x.f = f;
  u32 r = x.i + 0x7fffu + ((x.i >> 16) & 1u);   // RTNE
  return (u16)(r >> 16);
}
__device__ __forceinline__ void gl_lds16(const void* g, void* l) {
  __builtin_amdgcn_global_load_lds(
      (const __attribute__((address_space(1))) u32*)g,
      (__attribute__((address_space(3))) u32*)l, 16, 0, 0);
}

// ---------------- dtype detection ----------------
__global__ void detect(const void* __restrict__ latent, const void* __restrict__ seg,
                       u32* __restrict__ flags) {
  __shared__ int sane_cnt;
  __shared__ int seg_nz;
  if (threadIdx.x == 0) { sane_cnt = 0; seg_nz = 0; }
  __syncthreads();
  const u16* lu = (const u16*)latent;
  int local = 0;
  for (int i = threadIdx.x; i < 512; i += 256) {
    u16 u = lu[2 * i];
    int e = (u >> 7) & 0xFF;
    if (u == 0 || (e >= 90 && e <= 145)) local++;
  }
  atomicAdd(&sane_cnt, local);
  const int* s32 = (const int*)seg;
  int nz = 0;
  for (int i = threadIdx.x; i < 1000; i += 256)
    nz |= s32[6001 + 2 * i];
  atomicOr(&seg_nz, nz);
  __syncthreads();
  if (threadIdx.x == 0) {
    flags[0] = (sane_cnt >= 450) ? 1u : 0u;   // bf16?
    flags[1] = (seg_nz == 0) ? 1u : 0u;       // int64?
  }
}

// ---------------- preprocessing ----------------
__global__ void prep_masks(const void* __restrict__ seg, const u32* __restrict__ flags,
                           u32* __restrict__ masks) {
  int n = blockIdx.x * 256 + threadIdx.x;
  u32 b = 0;
  if (flags[1]) {
    const long long* s = (const long long*)seg;
    long long sn = s[n];
    #pragma unroll
    for (int k = 0; k < 9; ++k) {
      int m = n + k - 4;
      if (m >= 0 && m < NROW && s[m] == sn) b |= (1u << k);
    }
  } else {
    const int* s = (const int*)seg;
    int sn = s[n];
    #pragma unroll
    for (int k = 0; k < 9; ++k) {
      int m = n + k - 4;
      if (m >= 0 && m < NROW && s[m] == sn) b |= (1u << k);
    }
  }
  masks[n] = b;
}

__global__ void prep_x1t(const void* __restrict__ latent, const u32* __restrict__ flags,
                         u16* __restrict__ X1t) {
  int tid = blockIdx.x * 256 + threadIdx.x;     // 80*8192 threads
  int n = tid & (NROW - 1), g = tid >> 13;
  union { u16 o[8]; uint4 v; } u;
  u.v = make_uint4(0, 0, 0, 0);
  if (g < 75) {
    if (flags[0]) {
      u.v = *(const uint4*)((const u16*)latent + (size_t)n * 600 + g * 8);
    } else {
      const float* lf = (const float*)latent + (size_t)n * 600 + g * 8;
      float4 a = *(const float4*)lf;
      float4 b = *(const float4*)(lf + 4);
      u.o[0] = f2b(a.x); u.o[1] = f2b(a.y); u.o[2] = f2b(a.z); u.o[3] = f2b(a.w);
      u.o[4] = f2b(b.x); u.o[5] = f2b(b.y); u.o[6] = f2b(b.z); u.o[7] = f2b(b.w);
    }
  }
  *(uint4*)(X1t + ((size_t)g * NROW + n) * 8) = u.v;
}

// Wt[k][g][d][j] = w[d][8g+j][k] via LDS transpose; coalesced read & write.
// Tile stride 290 u16 (word-stride 145, odd) -> conflict-free transpose reads.
template<int CIN, int G>
__global__ void prep_wt(const void* __restrict__ w, const u32* __restrict__ flags,
                        u16* __restrict__ Wt) {
  __shared__ u16 tile[64 * 290];                 // [dr][m], m = (c-c0)*9+k
  int d0 = blockIdx.x * 64, c0 = blockIdx.y * 32;
  u32 isbf = flags[0];
  int mlim = (CIN - c0) * 9;
  #pragma unroll 1
  for (int it = 0; it < 72; ++it) {
    int e = it * 256 + threadIdx.x;
    int dr = e / 288, m = e - dr * 288;
    u16 val = 0;
    if (m < mlim) {
      size_t si = (size_t)(d0 + dr) * CIN * 9 + (size_t)c0 * 9 + m;
      val = isbf ? ((const u16*)w)[si] : f2b(((const float*)w)[si]);
    }
    tile[dr * 290 + m] = val;
  }
  __syncthreads();
  int g = threadIdx.x >> 6, dd = threadIdx.x & 63;
  #pragma unroll 1
  for (int k = 0; k < 9; ++k) {
    union { u16 o[8]; uint4 v; } u;
    #pragma unroll
    for (int j = 0; j < 8; ++j) u.o[j] = tile[dd * 290 + (g * 8 + j) * 9 + k];
    *(uint4*)(Wt + (((size_t)k * G + (c0 >> 3) + g) * DH + d0 + dd) * 8) = u.v;
  }
}

__device__ __forceinline__ float ldf(const void* p, int i, u32 isbf) {
  return isbf ? b2f(((const u16*)p)[i]) : ((const float*)p)[i];
}

__global__ void prep_bn(const void* __restrict__ b, const void* __restrict__ g,
                        const void* __restrict__ be, const void* __restrict__ m,
                        const void* __restrict__ v, const u32* __restrict__ flags,
                        float* __restrict__ bias_f, float* __restrict__ scale_f,
                        float* __restrict__ shift_f) {
  int i = blockIdx.x * 256 + threadIdx.x;
  u32 isbf = flags[0];
  float sc = ldf(g, i, isbf) * rsqrtf(ldf(v, i, isbf) + 1e-5f);
  bias_f[i]  = ldf(b, i, isbf);
  scale_f[i] = sc;
  shift_f[i] = ldf(be, i, isbf) - ldf(m, i, isbf) * sc;
}

// ---------------- main seg-conv GEMM ----------------
// Xt: [GTOT][NROW][8] bf16, Wt: [9][GTOT][DH][8] bf16.
// Grid: (DH/128, NROW/256), 256 threads = 2x2 waves of 128(row)x64(col) tiles.
// KB = GTOT/8 channel-super-blocks of 64 channels (8 groups).
// OM=0: grouped out [DH/8][NROW][8]; OM=1: row-major [NROW][DH].
template<int GTOT, int KB, int OM>
__launch_bounds__(256, 2)
__global__ void conv_gemm(const u16* __restrict__ Xt, const u16* __restrict__ Wt,
                          const u32* __restrict__ masks,
                          const float* __restrict__ bias_f,
                          const float* __restrict__ scale_f,
                          const float* __restrict__ shift_f,
                          u16* __restrict__ out) {
  __shared__ uint4 A_lds[8 * 264];       // [g][haloRow] flat, stride 264 (proven idiom)
  __shared__ uint4 B_lds[2][8 * 128];    // dbuf [g][col]

  const int tid  = threadIdx.x;
  // XCD-aware swizzle: HW dispatch id round-robins XCDs (xcd = flat % 8).
  // Bijective since nwg = 512 is a multiple of 8. Grid is fixed (16, 32).
  const int flat = (int)(blockIdx.y * gridDim.x + blockIdx.x);
  const int swz  = (flat & 7) * 64 + (flat >> 3);
  const int col0 = (swz >> 5) * 128;     // swz / 32 -> column panel
  const int row0 = (swz & 31) * 256;     // swz % 32 -> row block
  const int lane = tid & 63;
  const int wid  = tid >> 6;
  const int wr = wid >> 1, wc = wid & 1;       // 2x2 waves: 128 rows x 64 cols each
  const int l31 = lane & 31, g2 = lane >> 5;

  f32x16 acc[4][2] = {};

  u32 mb[4];
  #pragma unroll
  for (int i = 0; i < 4; ++i)
    mb[i] = masks[row0 + wr * 128 + i * 32 + l31];

  // wave-uniform "no segment boundary in this 32-row chunk" bits (skip cndmask)
  u32 cleanb = 0;
  #pragma unroll
  for (int i = 0; i < 4; ++i)
    cleanb |= (__all((int)(mb[i] == 0x1FFu)) ? 1u : 0u) << i;

  // per-thread LDS base pointers -> all fragment reads use immediate offsets
  const uint4* Abase = &A_lds[g2 * 264 + wr * 128 + l31];
  const uint4* Bbase = &B_lds[0][g2 * 128 + wc * 64 + l31];

  const int tot = KB * 9;

  #pragma unroll 1
  for (int cb = 0; cb < KB; ++cb) {
    // stage A halo: 8 groups x 264 rows (flat strided loop, proven idiom)
    for (int t = tid; t < 8 * 264; t += 256) {
      int g = t / 264;
      int h = t - g * 264;
      int xr = row0 - 4 + h;
      xr = xr < 0 ? 0 : (xr > NROW - 1 ? NROW - 1 : xr);
      gl_lds16(Xt + (((size_t)(cb * 8 + g)) * NROW + xr) * 8, &A_lds[t]);
    }
    if (cb == 0) {
      // stage B for (cb=0,k=0) into buf 0: 8 groups x 128 cols
      #pragma unroll
      for (int it2 = 0; it2 < 4; ++it2) {
        int t2 = it2 * 256 + tid;
        gl_lds16(Wt + (((size_t)(t2 >> 7)) * DH + col0 + (t2 & 127)) * 8, &B_lds[0][t2]);
      }
    }
    __syncthreads();

    #pragma unroll 1
    for (int k = 0; k < 9; ++k) {
      const int it = cb * 9 + k;
      // prefetch B for next iteration into the other buffer (in flight during MFMAs)
      if (it + 1 < tot) {
        int k2 = k + 1, cb2 = cb;
        if (k2 == 9) { k2 = 0; cb2 = cb + 1; }
        const u16* src = Wt + (((size_t)k2 * GTOT + cb2 * 8) * DH + col0) * 8;
        uint4* dst = B_lds[(it + 1) & 1];
        #pragma unroll
        for (int it2 = 0; it2 < 4; ++it2) {
          int t2 = it2 * 256 + tid;
          gl_lds16(src + ((size_t)(t2 >> 7) * DH + (t2 & 127)) * 8, &dst[t2]);
        }
      }

      const uint4* Ak = Abase + k;                       // h = wr*128 + i*32 + l31 + k
      const uint4* Bk = Bbase + (it & 1) * (8 * 128);    // current B buffer

      // 4 slabs, software-pipelined: load slab t+1 while MFMA'ing slab t.
      // slab t covers groups {2t, 2t+1} (lane g2 picks one) = one MFMA K=16 step.
      uint4 a_f[2][4];
      uint4 b_f[2][2];
      #pragma unroll
      for (int i = 0; i < 4; ++i) a_f[0][i] = Ak[i * 32];
      #pragma unroll
      for (int j = 0; j < 2; ++j) b_f[0][j] = Bk[j * 32];

      #pragma unroll
      for (int t = 0; t < 4; ++t) {
        const int cur = t & 1, nxt = cur ^ 1;
        if (t < 3) {
          #pragma unroll
          for (int i = 0; i < 4; ++i)
            a_f[nxt][i] = Ak[(2 * (t + 1)) * 264 + i * 32];
          #pragma unroll
          for (int j = 0; j < 2; ++j)
            b_f[nxt][j] = Bk[(2 * (t + 1)) * 128 + j * 32];
        }
        // segment-boundary masking (skipped wave-uniformly for clean chunks)
        #pragma unroll
        for (int i = 0; i < 4; ++i) {
          if (!((cleanb >> i) & 1)) {
            if (!((mb[i] >> k) & 1u)) a_f[cur][i] = make_uint4(0, 0, 0, 0);
          }
        }
        __builtin_amdgcn_s_setprio(1);
        #pragma unroll
        for (int i = 0; i < 4; ++i)
          #pragma unroll
          for (int j = 0; j < 2; ++j)
            acc[i][j] = __builtin_amdgcn_mfma_f32_32x32x16_bf16(
                __builtin_bit_cast(bf16x8, a_f[cur][i]),
                __builtin_bit_cast(bf16x8, b_f[cur][j]), acc[i][j], 0, 0, 0);
        __builtin_amdgcn_s_setprio(0);
      }

      __syncthreads();
    }
  }

  // epilogue: bias -> ReLU -> BN -> bf16 store
  float bc[2], sc[2], sh[2];
  int colv[2];
  #pragma unroll
  for (int j = 0; j < 2; ++j) {
    colv[j] = col0 + wc * 64 + j * 32 + l31;
    bc[j] = bias_f[colv[j]]; sc[j] = scale_f[colv[j]]; sh[j] = shift_f[colv[j]];
  }
  #pragma unroll
  for (int i = 0; i < 4; ++i) {
    #pragma unroll
    for (int j = 0; j < 2; ++j) {
      int col = colv[j];
      #pragma unroll
      for (int r = 0; r < 16; ++r) {
        int row = i * 32 + (r & 3) + 8 * (r >> 2) + 4 * g2;  // 32x32 C layout
        int n = row0 + wr * 128 + row;
        float v = acc[i][j][r] + bc[j];
        v = fmaxf(v, 0.f) * sc[j] + sh[j];
        u16 o = f2b(v);
        if (OM == 0) out[(((size_t)(col >> 3)) * NROW + n) * 8 + (col & 7)] = o;
        else         out[(size_t)n * DH + col] = o;
      }
    }
  }
}

// ---------------- final linear + softmax ----------------
__global__ void final_head(const u16* __restrict__ h2, const void* __restrict__ wlin,
                           const void* __restrict__ blin, const u32* __restrict__ flags,
                           void* __restrict__ out) {
  int row  = blockIdx.x * 4 + (threadIdx.x >> 6);
  int lane = threadIdx.x & 63;
  u32 isbf = flags[0];
  const u16* hr = h2 + (size_t)row * DH;
  float s0 = 0.f, s1 = 0.f;
  #pragma unroll
  for (int it = 0; it < 4; ++it) {
    int c = it * 512 + lane * 8;
    uint4 hv = *(const uint4*)(hr + c);
    const u16* hp = (const u16*)&hv;
    float w0v[8], w1v[8];
    if (isbf) {
      uint4 w0 = *(const uint4*)((const u16*)wlin + c);
      uint4 w1 = *(const uint4*)((const u16*)wlin + DH + c);
      const u16* p0 = (const u16*)&w0;
      const u16* p1 = (const u16*)&w1;
      #pragma unroll
      for (int j = 0; j < 8; ++j) { w0v[j] = b2f(p0[j]); w1v[j] = b2f(p1[j]); }
    } else {
      const float* f0 = (const float*)wlin + c;
      const float* f1 = (const float*)wlin + DH + c;
      float4 a0 = *(const float4*)f0, b0 = *(const float4*)(f0 + 4);
      float4 a1 = *(const float4*)f1, b1 = *(const float4*)(f1 + 4);
      w0v[0]=a0.x; w0v[1]=a0.y; w0v[2]=a0.z; w0v[3]=a0.w;
      w0v[4]=b0.x; w0v[5]=b0.y; w0v[6]=b0.z; w0v[7]=b0.w;
      w1v[0]=a1.x; w1v[1]=a1.y; w1v[2]=a1.z; w1v[3]=a1.w;
      w1v[4]=b1.x; w1v[5]=b1.y; w1v[6]=b1.z; w1v[7]=b1.w;
    }
    #pragma unroll
    for (int j = 0; j < 8; ++j) {
      float hf = b2f(hp[j]);
      s0 += hf * w0v[j];
      s1 += hf * w1v[j];
    }
  }
  #pragma unroll
  for (int off = 32; off >= 1; off >>= 1) {
    s0 += __shfl_down(s0, off);
    s1 += __shfl_down(s1, off);
  }
  if (lane == 0) {
    float o0 = s0 + ldf(blin, 0, isbf);
    float o1 = s1 + ldf(blin, 1, isbf);
    float mx = fmaxf(o0, o1);
    float e0 = expf(o0 - mx), e1 = expf(o1 - mx);
    float inv = 1.f / (e0 + e1);
    if (isbf) {
      u16* ob = (u16*)out;
      ob[(size_t)row * 2]              = f2b(o0);
      ob[(size_t)row * 2 + 1]          = f2b(o1);
      ob[16384 + (size_t)row * 2]      = f2b(e0 * inv);
      ob[16384 + (size_t)row * 2 + 1]  = f2b(e1 * inv);
    } else {
      float* of = (float*)out;
      of[(size_t)row * 2]              = o0;
      of[(size_t)row * 2 + 1]          = o1;
      of[16384 + (size_t)row * 2]      = e0 * inv;
      of[16384 + (size_t)row * 2 + 1]  = e1 * inv;
    }
  }
}

// ---------------- launch ----------------
extern "C" void kernel_launch(void* const* d_in, const int* in_sizes, int n_in,
                              void* d_out, int out_size, void* d_ws, size_t ws_size,
                              hipStream_t stream) {
  const void* latent = d_in[0];
  const void* seg    = d_in[1];
  const void* w1  = d_in[2];
  const void* b1  = d_in[3];
  const void* g1  = d_in[4];
  const void* be1 = d_in[5];
  const void* m1  = d_in[6];
  const void* v1  = d_in[7];
  const void* w2  = d_in[8];
  const void* b2  = d_in[9];
  const void* g2  = d_in[10];
  const void* be2 = d_in[11];
  const void* m2  = d_in[12];
  const void* v2  = d_in[13];
  const void* wlin = d_in[14];
  const void* blin = d_in[15];

  char* ws = (char*)d_ws;
  u32*   flags = (u32*)ws;                                   //        256
  u32*   masks = (u32*)(ws + 256);                           //      32768
  float* bn1   = (float*)(ws + 33024);                       //      24576
  float* bn2   = (float*)(ws + 57600);                       //      24576
  u16*   X1t   = (u16*)(ws + 82176);                         //   10485760  [80][8192][8]
  u16*   Wt1   = X1t + (size_t)80 * NROW * 8;                //   23592960  [9][80][2048][8]
  u16*   h1t   = Wt1 + (size_t)9 * 80 * DH * 8;              //   33554432  [256][8192][8]
  u16*   Wt2   = h1t + (size_t)256 * NROW * 8;               //   75497472  [9][256][2048][8]
  u16*   h2    = X1t;                                        // reuse dead X1t/Wt1 region

  detect<<<1, 256, 0, stream>>>(latent, seg, flags);
  prep_masks<<<NROW / 256, 256, 0, stream>>>(seg, flags, masks);
  prep_bn<<<DH / 256, 256, 0, stream>>>(b1, g1, be1, m1, v1, flags, bn1, bn1 + 2048, bn1 + 4096);
  prep_bn<<<DH / 256, 256, 0, stream>>>(b2, g2, be2, m2, v2, flags, bn2, bn2 + 2048, bn2 + 4096);
  prep_x1t<<<(80 * NROW) / 256, 256, 0, stream>>>(latent, flags, X1t);
  prep_wt<600, 80><<<dim3(DH / 64, 20), 256, 0, stream>>>(w1, flags, Wt1);
  prep_wt<2048, 256><<<dim3(DH / 64, 64), 256, 0, stream>>>(w2, flags, Wt2);

  dim3 grid(DH / 128, NROW / 256);
  conv_gemm<80, 10, 0><<<grid, 256, 0, stream>>>(X1t, Wt1, masks,
      bn1, bn1 + 2048, bn1 + 4096, h1t);
  conv_gemm<256, 32, 1><<<grid, 256, 0, stream>>>(h1t, Wt2, masks,
      bn2, bn2 + 2048, bn2 + 4096, h2);

  final_head<<<NROW / 4, 256, 0, stream>>>(h2, wlin, blin, flags, d_out);
}

// Round 3
// 1011.411 us; speedup vs baseline: 1.0775x; 1.0658x over previous
//
#include <hip/hip_runtime.h>

// PainHead: seg-masked conv(600->2048,K9) -> ReLU -> BN -> seg-masked conv(2048->2048,K9)
//           -> ReLU -> BN -> linear(2048->2) -> softmax.
// Runtime dtype detection (flags in ws): floats f32-vs-bf16, seg int64-vs-int32.
// GEMM core: mfma_f32_32x32x16_bf16. Block tile 256x128, 4 waves (2x2) of 128x64 wave
// tiles, grid 512 = 2 blocks/CU.
// R6: XCD-aware column-chunked block swizzle (bijective, 512%8==0).
// R7: slab software pipeline (+7%: 568->528 us, MfmaUtil 52->57).
// R8: B moved from LDS to REGISTERS loaded straight from global (L2-resident panel,
//     XCD swizzle localizes it). Eliminates the per-k __syncthreads entirely: the
//     k-loop has NO shared-memory writes (A read-only, B private regs) -> race-free
//     without barriers; only 2 barriers per channel-superblock remain (A restage WAR).
//     Waves free-run -> MFMA/LDS/VMEM overlap; LDS traffic -33% (24->16 ds_read/iter);
//     compiler inserts precise counted vmcnt for register B loads (T4 effect without
//     inline asm). Full k x slab unroll -> all A ds_read offsets are immediates.
//     Depth-2-slab register double buffer, static parity (36 slabs/cb, even).

typedef unsigned int   u32;
typedef unsigned short u16;
typedef __bf16 bf16x8 __attribute__((ext_vector_type(8)));
typedef float  f32x16 __attribute__((ext_vector_type(16)));

#define NROW 8192
#define DH   2048

__device__ __forceinline__ float b2f(u16 u) {
  union { u32 i; float f; } x; x.i = ((u32)u) << 16; return x.f;
}
__device__ __forceinline__ u16 f2b(float f) {
  union { float f; u32 i; } x; x.f = f;
  u32 r = x.i + 0x7fffu + ((x.i >> 16) & 1u);   // RTNE
  return (u16)(r >> 16);
}
__device__ __forceinline__ void gl_lds16(const void* g, void* l) {
  __builtin_amdgcn_global_load_lds(
      (const __attribute__((address_space(1))) u32*)g,
      (__attribute__((address_space(3))) u32*)l, 16, 0, 0);
}

// ---------------- dtype detection ----------------
__global__ void detect(const void* __restrict__ latent, const void* __restrict__ seg,
                       u32* __restrict__ flags) {
  __shared__ int sane_cnt;
  __shared__ int seg_nz;
  if (threadIdx.x == 0) { sane_cnt = 0; seg_nz = 0; }
  __syncthreads();
  const u16* lu = (const u16*)latent;
  int local = 0;
  for (int i = threadIdx.x; i < 512; i += 256) {
    u16 u = lu[2 * i];
    int e = (u >> 7) & 0xFF;
    if (u == 0 || (e >= 90 && e <= 145)) local++;
  }
  atomicAdd(&sane_cnt, local);
  const int* s32 = (const int*)seg;
  int nz = 0;
  for (int i = threadIdx.x; i < 1000; i += 256)
    nz |= s32[6001 + 2 * i];
  atomicOr(&seg_nz, nz);
  __syncthreads();
  if (threadIdx.x == 0) {
    flags[0] = (sane_cnt >= 450) ? 1u : 0u;   // bf16?
    flags[1] = (seg_nz == 0) ? 1u : 0u;       // int64?
  }
}

// ---------------- preprocessing ----------------
__global__ void prep_masks(const void* __restrict__ seg, const u32* __restrict__ flags,
                           u32* __restrict__ masks) {
  int n = blockIdx.x * 256 + threadIdx.x;
  u32 b = 0;
  if (flags[1]) {
    const long long* s = (const long long*)seg;
    long long sn = s[n];
    #pragma unroll
    for (int k = 0; k < 9; ++k) {
      int m = n + k - 4;
      if (m >= 0 && m < NROW && s[m] == sn) b |= (1u << k);
    }
  } else {
    const int* s = (const int*)seg;
    int sn = s[n];
    #pragma unroll
    for (int k = 0; k < 9; ++k) {
      int m = n + k - 4;
      if (m >= 0 && m < NROW && s[m] == sn) b |= (1u << k);
    }
  }
  masks[n] = b;
}

__global__ void prep_x1t(const void* __restrict__ latent, const u32* __restrict__ flags,
                         u16* __restrict__ X1t) {
  int tid = blockIdx.x * 256 + threadIdx.x;     // 80*8192 threads
  int n = tid & (NROW - 1), g = tid >> 13;
  union { u16 o[8]; uint4 v; } u;
  u.v = make_uint4(0, 0, 0, 0);
  if (g < 75) {
    if (flags[0]) {
      u.v = *(const uint4*)((const u16*)latent + (size_t)n * 600 + g * 8);
    } else {
      const float* lf = (const float*)latent + (size_t)n * 600 + g * 8;
      float4 a = *(const float4*)lf;
      float4 b = *(const float4*)(lf + 4);
      u.o[0] = f2b(a.x); u.o[1] = f2b(a.y); u.o[2] = f2b(a.z); u.o[3] = f2b(a.w);
      u.o[4] = f2b(b.x); u.o[5] = f2b(b.y); u.o[6] = f2b(b.z); u.o[7] = f2b(b.w);
    }
  }
  *(uint4*)(X1t + ((size_t)g * NROW + n) * 8) = u.v;
}

// Wt[k][g][d][j] = w[d][8g+j][k] via LDS transpose; coalesced read & write.
// Tile stride 290 u16 (word-stride 145, odd) -> conflict-free transpose reads.
template<int CIN, int G>
__global__ void prep_wt(const void* __restrict__ w, const u32* __restrict__ flags,
                        u16* __restrict__ Wt) {
  __shared__ u16 tile[64 * 290];                 // [dr][m], m = (c-c0)*9+k
  int d0 = blockIdx.x * 64, c0 = blockIdx.y * 32;
  u32 isbf = flags[0];
  int mlim = (CIN - c0) * 9;
  #pragma unroll 1
  for (int it = 0; it < 72; ++it) {
    int e = it * 256 + threadIdx.x;
    int dr = e / 288, m = e - dr * 288;
    u16 val = 0;
    if (m < mlim) {
      size_t si = (size_t)(d0 + dr) * CIN * 9 + (size_t)c0 * 9 + m;
      val = isbf ? ((const u16*)w)[si] : f2b(((const float*)w)[si]);
    }
    tile[dr * 290 + m] = val;
  }
  __syncthreads();
  int g = threadIdx.x >> 6, dd = threadIdx.x & 63;
  #pragma unroll 1
  for (int k = 0; k < 9; ++k) {
    union { u16 o[8]; uint4 v; } u;
    #pragma unroll
    for (int j = 0; j < 8; ++j) u.o[j] = tile[dd * 290 + (g * 8 + j) * 9 + k];
    *(uint4*)(Wt + (((size_t)k * G + (c0 >> 3) + g) * DH + d0 + dd) * 8) = u.v;
  }
}

__device__ __forceinline__ float ldf(const void* p, int i, u32 isbf) {
  return isbf ? b2f(((const u16*)p)[i]) : ((const float*)p)[i];
}

__global__ void prep_bn(const void* __restrict__ b, const void* __restrict__ g,
                        const void* __restrict__ be, const void* __restrict__ m,
                        const void* __restrict__ v, const u32* __restrict__ flags,
                        float* __restrict__ bias_f, float* __restrict__ scale_f,
                        float* __restrict__ shift_f) {
  int i = blockIdx.x * 256 + threadIdx.x;
  u32 isbf = flags[0];
  float sc = ldf(g, i, isbf) * rsqrtf(ldf(v, i, isbf) + 1e-5f);
  bias_f[i]  = ldf(b, i, isbf);
  scale_f[i] = sc;
  shift_f[i] = ldf(be, i, isbf) - ldf(m, i, isbf) * sc;
}

// ---------------- main seg-conv GEMM ----------------
// Xt: [GTOT][NROW][8] bf16, Wt: [9][GTOT][DH][8] bf16.
// Grid: (DH/128, NROW/256), 256 threads = 2x2 waves of 128(row)x64(col) tiles.
// KB = GTOT/8 channel-super-blocks of 64 channels (8 groups).
// OM=0: grouped out [DH/8][NROW][8]; OM=1: row-major [NROW][DH].
template<int GTOT, int KB, int OM>
__launch_bounds__(256, 2)
__global__ void conv_gemm(const u16* __restrict__ Xt, const u16* __restrict__ Wt,
                          const u32* __restrict__ masks,
                          const float* __restrict__ bias_f,
                          const float* __restrict__ scale_f,
                          const float* __restrict__ shift_f,
                          u16* __restrict__ out) {
  __shared__ uint4 A_lds[8 * 264];       // [g][haloRow] flat, stride 264 (proven idiom)

  const int tid  = threadIdx.x;
  // XCD-aware swizzle: HW dispatch id round-robins XCDs (xcd = flat % 8).
  // Bijective since nwg = 512 is a multiple of 8. Grid is fixed (16, 32).
  const int flat = (int)(blockIdx.y * gridDim.x + blockIdx.x);
  const int swz  = (flat & 7) * 64 + (flat >> 3);
  const int col0 = (swz >> 5) * 128;     // swz / 32 -> column panel
  const int row0 = (swz & 31) * 256;     // swz % 32 -> row block
  const int lane = tid & 63;
  const int wid  = tid >> 6;
  const int wr = wid >> 1, wc = wid & 1;       // 2x2 waves: 128 rows x 64 cols each
  const int l31 = lane & 31, g2 = lane >> 5;

  f32x16 acc[4][2] = {};

  u32 mb[4];
  #pragma unroll
  for (int i = 0; i < 4; ++i)
    mb[i] = masks[row0 + wr * 128 + i * 32 + l31];

  // wave-uniform "no segment boundary in this 32-row chunk" bits (skip cndmask)
  u32 cleanb = 0;
  #pragma unroll
  for (int i = 0; i < 4; ++i)
    cleanb |= (__all((int)(mb[i] == 0x1FFu)) ? 1u : 0u) << i;

  // per-thread LDS base pointer -> all A fragment reads use immediate offsets
  const uint4* Abase = &A_lds[g2 * 264 + wr * 128 + l31];

  // per-lane B element offsets (u16 units) for slab t (groups 2t+g2), frag j
  u32 voffB[4][2];
  #pragma unroll
  for (int t = 0; t < 4; ++t)
    #pragma unroll
    for (int j = 0; j < 2; ++j)
      voffB[t][j] = (u32)(((2 * t + g2) * DH + wc * 64 + j * 32 + l31) * 8);

  uint4 bq[2][2];   // depth-2-slab register double buffer, static parity s&1

  #pragma unroll 1
  for (int cb = 0; cb < KB; ++cb) {
    // uniform base for this cb (col0 folded in); k advances by GTOT*DH*8 elements
    const u16* wbase = Wt + ((size_t)cb * 8 * DH + col0) * 8;

    // prologue: issue B loads for slabs 0,1 of this cb (land during A staging)
    #pragma unroll
    for (int s = 0; s < 2; ++s)
      #pragma unroll
      for (int j = 0; j < 2; ++j)
        bq[s][j] = *(const uint4*)(wbase + voffB[s][j]);   // k=0, t=s

    __syncthreads();   // all waves done reading previous A
    // stage A halo: 8 groups x 264 rows (flat strided loop, proven idiom)
    for (int t = tid; t < 8 * 264; t += 256) {
      int g = t / 264;
      int h = t - g * 264;
      int xr = row0 - 4 + h;
      xr = xr < 0 ? 0 : (xr > NROW - 1 ? NROW - 1 : xr);
      gl_lds16(Xt + (((size_t)(cb * 8 + g)) * NROW + xr) * 8, &A_lds[t]);
    }
    __syncthreads();   // A visible (drains vmcnt incl. prologue B loads)

    // 36 slabs (9 k-taps x 4 group-pairs), fully unrolled, no barriers inside:
    // A read-only, B in private registers -> race-free free-running waves.
    #pragma unroll
    for (int s = 0; s < 36; ++s) {
      const int k = s >> 2, t = s & 3;

      uint4 b0 = bq[s & 1][0];
      uint4 b1 = bq[s & 1][1];

      // prefetch slab s+2 (same parity slot; SSA under full unroll)
      if (s + 2 < 36) {
        const int k2 = (s + 2) >> 2, t2 = (s + 2) & 3;
        #pragma unroll
        for (int j = 0; j < 2; ++j)
          bq[s & 1][j] =
              *(const uint4*)(wbase + (size_t)k2 * GTOT * DH * 8 + voffB[t2][j]);
      }

      uint4 a_f[4];
      #pragma unroll
      for (int i = 0; i < 4; ++i) {
        a_f[i] = Abase[(2 * t) * 264 + i * 32 + k];   // imm-offset ds_read_b128
        if (!((cleanb >> i) & 1)) {
          if (!((mb[i] >> k) & 1u)) a_f[i] = make_uint4(0, 0, 0, 0);
        }
      }

      __builtin_amdgcn_s_setprio(1);
      #pragma unroll
      for (int i = 0; i < 4; ++i) {
        acc[i][0] = __builtin_amdgcn_mfma_f32_32x32x16_bf16(
            __builtin_bit_cast(bf16x8, a_f[i]),
            __builtin_bit_cast(bf16x8, b0), acc[i][0], 0, 0, 0);
        acc[i][1] = __builtin_amdgcn_mfma_f32_32x32x16_bf16(
            __builtin_bit_cast(bf16x8, a_f[i]),
            __builtin_bit_cast(bf16x8, b1), acc[i][1], 0, 0, 0);
      }
      __builtin_amdgcn_s_setprio(0);
    }
  }

  // epilogue: bias -> ReLU -> BN -> bf16 store
  float bc[2], sc[2], sh[2];
  int colv[2];
  #pragma unroll
  for (int j = 0; j < 2; ++j) {
    colv[j] = col0 + wc * 64 + j * 32 + l31;
    bc[j] = bias_f[colv[j]]; sc[j] = scale_f[colv[j]]; sh[j] = shift_f[colv[j]];
  }
  #pragma unroll
  for (int i = 0; i < 4; ++i) {
    #pragma unroll
    for (int j = 0; j < 2; ++j) {
      int col = colv[j];
      #pragma unroll
      for (int r = 0; r < 16; ++r) {
        int row = i * 32 + (r & 3) + 8 * (r >> 2) + 4 * g2;  // 32x32 C layout
        int n = row0 + wr * 128 + row;
        float v = acc[i][j][r] + bc[j];
        v = fmaxf(v, 0.f) * sc[j] + sh[j];
        u16 o = f2b(v);
        if (OM == 0) out[(((size_t)(col >> 3)) * NROW + n) * 8 + (col & 7)] = o;
        else         out[(size_t)n * DH + col] = o;
      }
    }
  }
}

// ---------------- final linear + softmax ----------------
__global__ void final_head(const u16* __restrict__ h2, const void* __restrict__ wlin,
                           const void* __restrict__ blin, const u32* __restrict__ flags,
                           void* __restrict__ out) {
  int row  = blockIdx.x * 4 + (threadIdx.x >> 6);
  int lane = threadIdx.x & 63;
  u32 isbf = flags[0];
  const u16* hr = h2 + (size_t)row * DH;
  float s0 = 0.f, s1 = 0.f;
  #pragma unroll
  for (int it = 0; it < 4; ++it) {
    int c = it * 512 + lane * 8;
    uint4 hv = *(const uint4*)(hr + c);
    const u16* hp = (const u16*)&hv;
    float w0v[8], w1v[8];
    if (isbf) {
      uint4 w0 = *(const uint4*)((const u16*)wlin + c);
      uint4 w1 = *(const uint4*)((const u16*)wlin + DH + c);
      const u16* p0 = (const u16*)&w0;
      const u16* p1 = (const u16*)&w1;
      #pragma unroll
      for (int j = 0; j < 8; ++j) { w0v[j] = b2f(p0[j]); w1v[j] = b2f(p1[j]); }
    } else {
      const float* f0 = (const float*)wlin + c;
      const float* f1 = (const float*)wlin + DH + c;
      float4 a0 = *(const float4*)f0, b0 = *(const float4*)(f0 + 4);
      float4 a1 = *(const float4*)f1, b1 = *(const float4*)(f1 + 4);
      w0v[0]=a0.x; w0v[1]=a0.y; w0v[2]=a0.z; w0v[3]=a0.w;
      w0v[4]=b0.x; w0v[5]=b0.y; w0v[6]=b0.z; w0v[7]=b0.w;
      w1v[0]=a1.x; w1v[1]=a1.y; w1v[2]=a1.z; w1v[3]=a1.w;
      w1v[4]=b1.x; w1v[5]=b1.y; w1v[6]=b1.z; w1v[7]=b1.w;
    }
    #pragma unroll
    for (int j = 0; j < 8; ++j) {
      float hf = b2f(hp[j]);
      s0 += hf * w0v[j];
      s1 += hf * w1v[j];
    }
  }
  #pragma unroll
  for (int off = 32; off >= 1; off >>= 1) {
    s0 += __shfl_down(s0, off);
    s1 += __shfl_down(s1, off);
  }
  if (lane == 0) {
    float o0 = s0 + ldf(blin, 0, isbf);
    float o1 = s1 + ldf(blin, 1, isbf);
    float mx = fmaxf(o0, o1);
    float e0 = expf(o0 - mx), e1 = expf(o1 - mx);
    float inv = 1.f / (e0 + e1);
    if (isbf) {
      u16* ob = (u16*)out;
      ob[(size_t)row * 2]              = f2b(o0);
      ob[(size_t)row * 2 + 1]          = f2b(o1);
      ob[16384 + (size_t)row * 2]      = f2b(e0 * inv);
      ob[16384 + (size_t)row * 2 + 1]  = f2b(e1 * inv);
    } else {
      float* of = (float*)out;
      of[(size_t)row * 2]              = o0;
      of[(size_t)row * 2 + 1]          = o1;
      of[16384 + (size_t)row * 2]      = e0 * inv;
      of[16384 + (size_t)row * 2 + 1]  = e1 * inv;
    }
  }
}

// ---------------- launch ----------------
extern "C" void kernel_launch(void* const* d_in, const int* in_sizes, int n_in,
                              void* d_out, int out_size, void* d_ws, size_t ws_size,
                              hipStream_t stream) {
  const void* latent = d_in[0];
  const void* seg    = d_in[1];
  const void* w1  = d_in[2];
  const void* b1  = d_in[3];
  const void* g1  = d_in[4];
  const void* be1 = d_in[5];
  const void* m1  = d_in[6];
  const void* v1  = d_in[7];
  const void* w2  = d_in[8];
  const void* b2  = d_in[9];
  const void* g2  = d_in[10];
  const void* be2 = d_in[11];
  const void* m2  = d_in[12];
  const void* v2  = d_in[13];
  const void* wlin = d_in[14];
  const void* blin = d_in[15];

  char* ws = (char*)d_ws;
  u32*   flags = (u32*)ws;                                   //        256
  u32*   masks = (u32*)(ws + 256);                           //      32768
  float* bn1   = (float*)(ws + 33024);                       //      24576
  float* bn2   = (float*)(ws + 57600);                       //      24576
  u16*   X1t   = (u16*)(ws + 82176);                         //   10485760  [80][8192][8]
  u16*   Wt1   = X1t + (size_t)80 * NROW * 8;                //   23592960  [9][80][2048][8]
  u16*   h1t   = Wt1 + (size_t)9 * 80 * DH * 8;              //   33554432  [256][8192][8]
  u16*   Wt2   = h1t + (size_t)256 * NROW * 8;               //   75497472  [9][256][2048][8]
  u16*   h2    = X1t;                                        // reuse dead X1t/Wt1 region

  detect<<<1, 256, 0, stream>>>(latent, seg, flags);
  prep_masks<<<NROW / 256, 256, 0, stream>>>(seg, flags, masks);
  prep_bn<<<DH / 256, 256, 0, stream>>>(b1, g1, be1, m1, v1, flags, bn1, bn1 + 2048, bn1 + 4096);
  prep_bn<<<DH / 256, 256, 0, stream>>>(b2, g2, be2, m2, v2, flags, bn2, bn2 + 2048, bn2 + 4096);
  prep_x1t<<<(80 * NROW) / 256, 256, 0, stream>>>(latent, flags, X1t);
  prep_wt<600, 80><<<dim3(DH / 64, 20), 256, 0, stream>>>(w1, flags, Wt1);
  prep_wt<2048, 256><<<dim3(DH / 64, 64), 256, 0, stream>>>(w2, flags, Wt2);

  dim3 grid(DH / 128, NROW / 256);
  conv_gemm<80, 10, 0><<<grid, 256, 0, stream>>>(X1t, Wt1, masks,
      bn1, bn1 + 2048, bn1 + 4096, h1t);
  conv_gemm<256, 32, 1><<<grid, 256, 0, stream>>>(h1t, Wt2, masks,
      bn2, bn2 + 2048, bn2 + 4096, h2);

  final_head<<<NROW / 4, 256, 0, stream>>>(h2, wlin, blin, flags, d_out);
}